// Round 3
// baseline (54.598 us; speedup 1.0000x reference)
//
#include <hip/hip_runtime.h>
#include <hip/hip_bf16.h>
#include <stdint.h>

// KANLayer as GEMM: out[8192,512] = A[8192,1536]@W[1536,512] + bias, bf16 MFMA, fp32 accum.
// K-order: 16 groups of 96; group g covers i in [g*32,g*32+32) x p in {0,1,2} (ks = g*3+p).
// A-fragments computed IN-REGISTER from x (powers + bf16 cvt); only W goes through LDS.

static constexpr int ON_ = 512;
static constexpr int NGR = 16;    // 16 groups x 3 k-steps x K=32 = 1536

typedef __bf16 bf16x8 __attribute__((ext_vector_type(8)));
typedef float  f32x4  __attribute__((ext_vector_type(4)));

__device__ __forceinline__ unsigned int f2bf(float f) {
    unsigned int u = __float_as_uint(f);
    return ((u + 0x7FFFu + ((u >> 16) & 1u)) >> 16);   // RNE bf16, finite inputs
}

__device__ __forceinline__ void gld_lds16(const void* g, void* l) {
    __builtin_amdgcn_global_load_lds(
        (const __attribute__((address_space(1))) unsigned int*)(uintptr_t)g,
        (__attribute__((address_space(3))) unsigned int*)(unsigned int)(uintptr_t)l,
        16, 0, 0);
}

// ---- pack B (blocks 0..383) + bias (blocks 384..391).
// Chunk (cb, ks) at Bpk[(cb*48+ks)*1024]: lane l holds W[k][cb*16+(l&15)], k-in-chunk=(l>>4)*8+j.
// ks = ic*3 + p  ->  i0 = (ks/3)*32, p = ks%3.
__global__ __launch_bounds__(256) void pack_B_bias(const float* __restrict__ edge_w, const float* __restrict__ comb_w,
                                                   const float* __restrict__ edge_b,
                                                   uint4* __restrict__ Bpk, float* __restrict__ bias) {
    if (blockIdx.x < 384) {
        int id   = blockIdx.x * 256 + threadIdx.x;  // ((cb*48)+ks)*64 + l
        int l    = id & 63;
        int cbks = id >> 6;
        int ks   = cbks % 48;
        int cb   = cbks / 48;
        int o    = cb * 16 + (l & 15);
        int p    = ks % 3;
        int i0   = (ks / 3) * 32 + ((l >> 4) << 3);
        unsigned int w[4];
#pragma unroll
        for (int j = 0; j < 4; ++j) {
            int ia = i0 + 2 * j, ic = ia + 1;
            float va = edge_w[((size_t)ia * ON_ + o) * 3 + p] * comb_w[(size_t)ia * ON_ + o];
            float vc = edge_w[((size_t)ic * ON_ + o) * 3 + p] * comb_w[(size_t)ic * ON_ + o];
            w[j] = f2bf(va) | (f2bf(vc) << 16);
        }
        Bpk[id] = make_uint4(w[0], w[1], w[2], w[3]);
    } else {
        __shared__ float red[4][64];
        int bo = blockIdx.x - 384;          // 0..7, 64 o's each
        int tt = threadIdx.x;
        int o  = bo * 64 + (tt & 63);
        int iseg = tt >> 6;
        float s = 0.f;
        int ib = iseg * 128;
#pragma unroll 4
        for (int i = ib; i < ib + 128; ++i)
            s += comb_w[(size_t)i * ON_ + o] * edge_b[(size_t)i * ON_ + o];
        red[iseg][tt & 63] = s;
        __syncthreads();
        if (tt < 64)
            bias[bo * 64 + tt] = red[0][tt] + red[1][tt] + red[2][tt] + red[3][tt];
    }
}

// ---- fused GEMM: BM=128, BN=64, 4 waves (2x2), wave tile 64x32.
// Per group: 8 x-loads (float4) -> 3 power-steps of A-frags in reg; 3 B-chunks via gld_lds,
// 3-deep LDS buffers, one s_barrier + counted vmcnt(11) per group. 16 groups fully unrolled.
__global__ __launch_bounds__(256, 2) void gemm_fused(const float* __restrict__ x,
                                                     const char* __restrict__ Bpk,
                                                     const float* __restrict__ bias,
                                                     float* __restrict__ out) {
    __shared__ char lds[3][12288];   // [buf][step p 0..2 (4KB)][cb_local 0..3 (1KB)][lane][16B]
    const int tid = threadIdx.x;
    const int l   = tid & 63;
    const int wid = tid >> 6;
    const int wr  = wid >> 1, wc = wid & 1;

    // bijective XCD swizzle (512 blocks % 8 == 0): XCD owns contiguous bx range -> x panels L2-local
    int d  = blockIdx.x;
    int w  = (d & 7) * 64 + (d >> 3);
    int bx = w >> 3, by = w & 7;

    // B source: this wave stages cb_local = wid (global cb = by*4+wid); per-lane addr, linear LDS dest
    const char* gb = Bpk + ((size_t)(by * 4 + wid) * 48) * 1024 + (l << 4);
    // x bases: lane l covers rows bx*128+wr*64+m*16+(l&15), k-offset (l>>4)*8 within each 32-wide i-chunk
    const float* xgm[4];
    {
        int brow = bx * 128 + wr * 64 + (l & 15);
        int koff = (l >> 4) << 3;
#pragma unroll
        for (int m = 0; m < 4; ++m)
            xgm[m] = x + (size_t)(brow + m * 16) * 512 + koff;
    }

    f32x4  acc[4][2] = {};
    float4 xb[2][4][2];   // [parity][m][half] — all indices compile-time (full unroll)

    // prologue: x(0) + B(0) into buf 0
#pragma unroll
    for (int m = 0; m < 4; ++m) {
        xb[0][m][0] = *(const float4*)(xgm[m]);
        xb[0][m][1] = *(const float4*)(xgm[m] + 4);
    }
    {
        char* dl = (char*)lds + (wid << 10);
        gld_lds16(gb,        dl);
        gld_lds16(gb + 1024, dl + 4096);
        gld_lds16(gb + 2048, dl + 8192);
    }

#pragma unroll
    for (int g = 0; g < NGR; ++g) {
        if (g + 1 < NGR) {
            const int pr = (g + 1) & 1;
#pragma unroll
            for (int m = 0; m < 4; ++m) {
                xb[pr][m][0] = *(const float4*)(xgm[m] + (g + 1) * 32);
                xb[pr][m][1] = *(const float4*)(xgm[m] + (g + 1) * 32 + 4);
            }
            const char* gsrc = gb + (size_t)(g + 1) * 3072;
            char* dl = (char*)lds + ((g + 1) % 3) * 12288 + (wid << 10);
            gld_lds16(gsrc,        dl);
            gld_lds16(gsrc + 1024, dl + 4096);
            gld_lds16(gsrc + 2048, dl + 8192);
            asm volatile("s_waitcnt vmcnt(11)" ::: "memory");   // keep next group's 8 x + 3 B in flight
        } else {
            asm volatile("s_waitcnt vmcnt(0)" ::: "memory");
        }
        __builtin_amdgcn_s_barrier();

        // A-fragments for this group: powers of x, hw bf16 cvt (compiler pairs into v_cvt_pk_bf16_f32)
        const int pc = g & 1;
        bf16x8 af[3][4];
#pragma unroll
        for (int m = 0; m < 4; ++m) {
            float e[8] = {xb[pc][m][0].x, xb[pc][m][0].y, xb[pc][m][0].z, xb[pc][m][0].w,
                          xb[pc][m][1].x, xb[pc][m][1].y, xb[pc][m][1].z, xb[pc][m][1].w};
#pragma unroll
            for (int j = 0; j < 8; ++j) {
                float s = e[j], s2 = s * s;
                af[0][m][j] = (__bf16)s;
                af[1][m][j] = (__bf16)s2;
                af[2][m][j] = (__bf16)(s2 * s);
            }
        }

        const char* lb = (char*)lds + (g % 3) * 12288;
#pragma unroll
        for (int p = 0; p < 3; ++p) {
#pragma unroll
            for (int n = 0; n < 2; ++n) {
                bf16x8 bf = *(const bf16x8*)(lb + (p << 12) + (((wc << 1) + n) << 10) + (l << 4));
#pragma unroll
                for (int m = 0; m < 4; ++m)
                    acc[m][n] = __builtin_amdgcn_mfma_f32_16x16x32_bf16(af[p][m], bf, acc[m][n], 0, 0, 0);
            }
        }
    }

    // epilogue: C/D layout col=lane&15, row=(lane>>4)*4+reg
    int lr = l >> 4, lc = l & 15;
#pragma unroll
    for (int n = 0; n < 2; ++n) {
        int o = (by << 6) + (wc << 5) + (n << 4) + lc;
        float bv = bias[o];
#pragma unroll
        for (int m = 0; m < 4; ++m) {
            int r0 = (bx << 7) + (wr << 6) + (m << 4) + (lr << 2);
#pragma unroll
            for (int j = 0; j < 4; ++j)
                out[(size_t)(r0 + j) * ON_ + o] = acc[m][n][j] + bv;
        }
    }
}

extern "C" void kernel_launch(void* const* d_in, const int* in_sizes, int n_in,
                              void* d_out, int out_size, void* d_ws, size_t ws_size,
                              hipStream_t stream) {
    const float* x      = (const float*)d_in[0];
    const float* edge_w = (const float*)d_in[1];
    const float* edge_b = (const float*)d_in[2];
    const float* comb_w = (const float*)d_in[3];
    float* out = (float*)d_out;

    char* ws = (char*)d_ws;
    char* Bpk   = ws;                        // 1536*512*2 = 1,572,864 B
    float* bias = (float*)(ws + 1572864);    // 512*4 B

    hipLaunchKernelGGL(pack_B_bias, dim3(384 + 8), dim3(256), 0, stream, edge_w, comb_w, edge_b, (uint4*)Bpk, bias);
    hipLaunchKernelGGL(gemm_fused, dim3(512), dim3(256), 0, stream, x, Bpk, bias, out);
}

// Round 4
// 42.206 us; speedup vs baseline: 1.2936x; 1.2936x over previous
//
#include <hip/hip_runtime.h>
#include <hip/hip_bf16.h>
#include <stdint.h>

// KANLayer as GEMM: out[8192,512] = A[8192,1536]@W[1536,512] + bias, bf16 MFMA, fp32 accum.
// K-order: 16 groups of 96; group g covers i in [g*32,g*32+32) x p in {0,1,2} (chunk ks = g*3+p).
// A-fragments computed IN-REGISTER from x (running powers + hw bf16 cvt); only W goes through LDS.
// GEMM: BM=128, BN=64, 4 waves, wave-tile 32x64 (m=2,n=4). Named-reg x double-buffer (rule #20 safe),
// 3-deep B LDS pipeline, stage-ahead-1, uniform counted vmcnt(7).

static constexpr int ON_ = 512;

typedef __bf16 bf16x8 __attribute__((ext_vector_type(8)));
typedef float  f32x4  __attribute__((ext_vector_type(4)));

__device__ __forceinline__ unsigned int f2bf(float f) {
    unsigned int u = __float_as_uint(f);
    return ((u + 0x7FFFu + ((u >> 16) & 1u)) >> 16);   // RNE bf16, finite inputs
}

__device__ __forceinline__ float4 mul4(float4 a, float4 b) {
    return make_float4(a.x * b.x, a.y * b.y, a.z * b.z, a.w * b.w);
}

__device__ __forceinline__ void gld_lds16(const void* g, void* l) {
    __builtin_amdgcn_global_load_lds(
        (const __attribute__((address_space(1))) unsigned int*)(uintptr_t)g,
        (__attribute__((address_space(3))) unsigned int*)(unsigned int)(uintptr_t)l,
        16, 0, 0);
}

// ---- pack B (blocks 0..127) + bias (blocks 128..135).
// Chunk (cb, ks=g*3+p) at Bpk[(cb*48+ks)*1024]: lane l holds W[k][cb*16+(l&15)], k-in-chunk=(l>>4)*8+j.
// One thread covers an (i-pair, o) for ALL 3 powers: edge_w[i][o][0..2] read contiguously.
__global__ __launch_bounds__(256) void pack_B_bias(const float* __restrict__ edge_w, const float* __restrict__ comb_w,
                                                   const float* __restrict__ edge_b,
                                                   uint4* __restrict__ Bpk, float* __restrict__ bias) {
    if (blockIdx.x < 128) {
        int id = blockIdx.x * 256 + threadIdx.x;
        int l  = id & 63;
        int t  = id >> 6;          // 0..511
        int g  = t & 15;
        int cb = t >> 4;           // 0..31
        int o  = cb * 16 + (l & 15);
        int i0 = g * 32 + ((l >> 4) << 3);
        unsigned int w[3][4];
#pragma unroll
        for (int j = 0; j < 4; ++j) {
            int ia = i0 + 2 * j, ic = ia + 1;
            float ca = comb_w[(size_t)ia * ON_ + o];
            float cc = comb_w[(size_t)ic * ON_ + o];
            const float* ea = edge_w + ((size_t)ia * ON_ + o) * 3;
            const float* ec = edge_w + ((size_t)ic * ON_ + o) * 3;
#pragma unroll
            for (int p = 0; p < 3; ++p)
                w[p][j] = f2bf(ea[p] * ca) | (f2bf(ec[p] * cc) << 16);
        }
        size_t base = ((size_t)cb * 48 + g * 3) * 64 + l;
        Bpk[base]       = make_uint4(w[0][0], w[0][1], w[0][2], w[0][3]);
        Bpk[base + 64]  = make_uint4(w[1][0], w[1][1], w[1][2], w[1][3]);
        Bpk[base + 128] = make_uint4(w[2][0], w[2][1], w[2][2], w[2][3]);
    } else {
        __shared__ float red[4][64];
        int bo = blockIdx.x - 128;          // 0..7, 64 o's each
        int tt = threadIdx.x;
        int o  = bo * 64 + (tt & 63);
        int iseg = tt >> 6;
        float s = 0.f;
        int ib = iseg * 128;
#pragma unroll 4
        for (int i = ib; i < ib + 128; ++i)
            s += comb_w[(size_t)i * ON_ + o] * edge_b[(size_t)i * ON_ + o];
        red[iseg][tt & 63] = s;
        __syncthreads();
        if (tt < 64)
            bias[bo * 64 + tt] = red[0][tt] + red[1][tt] + red[2][tt] + red[3][tt];
    }
}

// Convert float4 pair (8 f32) -> bf16x8 via hw v_cvt (compiler pairs into v_cvt_pk_bf16_f32)
#define CVT8(D, LO, HI) do {                                                     \
    D = (bf16x8){ (__bf16)(LO).x, (__bf16)(LO).y, (__bf16)(LO).z, (__bf16)(LO).w, \
                  (__bf16)(HI).x, (__bf16)(HI).y, (__bf16)(HI).z, (__bf16)(HI).w }; \
} while (0)

// One group-step. C*/N* are NAMED float4 register buffers (compile-time, no spill).
// Issues exactly 7 VMEM ops (4 x-loads + 3 global_load_lds) when G+1<16.
#define STEP(G, C0, C1, C2, C3, N0, N1, N2, N3, WAITS) do {                      \
    if ((G) + 1 < 16) {                                                          \
        const float* xa_ = xg0 + ((G) + 1) * 32;                                 \
        const float* xc_ = xg1 + ((G) + 1) * 32;                                 \
        N0 = *(const float4*)(xa_);                                              \
        N1 = *(const float4*)(xa_ + 4);                                          \
        N2 = *(const float4*)(xc_);                                              \
        N3 = *(const float4*)(xc_ + 4);                                          \
        const char* gs_ = gb + (size_t)((G) + 1) * 3072;                         \
        char* dl_ = (char*)lds + so + (wid << 10);                               \
        gld_lds16(gs_,        dl_);                                             \
        gld_lds16(gs_ + 1024, dl_ + 4096);                                      \
        gld_lds16(gs_ + 2048, dl_ + 8192);                                      \
    }                                                                            \
    asm volatile("s_waitcnt " WAITS ::: "memory");                               \
    __builtin_amdgcn_s_barrier();                                                \
    {                                                                            \
        float4 p0 = C0, p1 = C1, p2 = C2, p3 = C3;                               \
        _Pragma("unroll")                                                        \
        for (int p = 0; p < 3; ++p) {                                            \
            bf16x8 a0_, a1_;                                                     \
            CVT8(a0_, p0, p1);                                                   \
            CVT8(a1_, p2, p3);                                                   \
            if (p < 2) { p0 = mul4(p0, C0); p1 = mul4(p1, C1);                   \
                         p2 = mul4(p2, C2); p3 = mul4(p3, C3); }                 \
            _Pragma("unroll")                                                    \
            for (int n = 0; n < 4; ++n) {                                        \
                bf16x8 bf_ = *(const bf16x8*)((char*)lds + co + (p << 12) + (n << 10) + (l << 4)); \
                acc[0][n] = __builtin_amdgcn_mfma_f32_16x16x32_bf16(a0_, bf_, acc[0][n], 0, 0, 0); \
                acc[1][n] = __builtin_amdgcn_mfma_f32_16x16x32_bf16(a1_, bf_, acc[1][n], 0, 0, 0); \
            }                                                                    \
        }                                                                        \
    }                                                                            \
    co = (co == 24576) ? 0 : co + 12288;                                         \
    so = (so == 24576) ? 0 : so + 12288;                                         \
} while (0)

__global__ __launch_bounds__(256, 2) void gemm_fused(const float* __restrict__ x,
                                                     const char* __restrict__ Bpk,
                                                     const float* __restrict__ bias,
                                                     float* __restrict__ out) {
    __shared__ char lds[36864];   // 3 bufs x 12KB; buf: [p 0..2 (4KB)][cb_local 0..3 (1KB)][lane][16B]
    const int tid = threadIdx.x;
    const int l   = tid & 63;
    const int wid = tid >> 6;     // wave row-strip 0..3

    // bijective XCD swizzle (512 % 8 == 0): XCD owns contiguous bx range -> x slice (2MB) L2-resident
    int d  = blockIdx.x;
    int w  = (d & 7) * 64 + (d >> 3);
    int bx = w >> 3, by = w & 7;

    const char* gb = Bpk + ((size_t)(by * 4 + wid) * 48) * 1024 + (l << 4);
    // lane l, m: row = bx*128 + wid*32 + m*16 + (l&15); cols (l>>4)*8 .. +7 within each 32-wide i-chunk
    const float* xg0 = x + (size_t)(bx * 128 + wid * 32 + (l & 15)) * 512 + ((l >> 4) << 3);
    const float* xg1 = xg0 + 16 * 512;

    f32x4 acc[2][4] = {};                      // [m][n], all indices compile-time
    float4 xA0, xA1, xA2, xA3, xB0, xB1, xB2, xB3;

    // prologue: x(0) -> A regs; stage B(0) at LDS offset 0   (7 VMEM ops, matches steady count)
    xA0 = *(const float4*)(xg0);
    xA1 = *(const float4*)(xg0 + 4);
    xA2 = *(const float4*)(xg1);
    xA3 = *(const float4*)(xg1 + 4);
    {
        char* dl = (char*)lds + (wid << 10);
        gld_lds16(gb,        dl);
        gld_lds16(gb + 1024, dl + 4096);
        gld_lds16(gb + 2048, dl + 8192);
    }

    int co = 0, so = 12288;

    for (int gp = 0; gp < 7; ++gp) {           // g = 0..13
        STEP(2 * gp,     xA0, xA1, xA2, xA3, xB0, xB1, xB2, xB3, "vmcnt(7)");
        STEP(2 * gp + 1, xB0, xB1, xB2, xB3, xA0, xA1, xA2, xA3, "vmcnt(7)");
    }
    STEP(14, xA0, xA1, xA2, xA3, xB0, xB1, xB2, xB3, "vmcnt(7)");
    STEP(15, xB0, xB1, xB2, xB3, xA0, xA1, xA2, xA3, "vmcnt(0)");

    // epilogue: C/D layout col=lane&15, row=(lane>>4)*4+reg
    int lr = l >> 4, lc = l & 15;
#pragma unroll
    for (int n = 0; n < 4; ++n) {
        int o = (by << 6) + (n << 4) + lc;
        float bv = bias[o];
#pragma unroll
        for (int m = 0; m < 2; ++m) {
            int r0 = (bx << 7) + (wid << 5) + (m << 4) + (lr << 2);
#pragma unroll
            for (int j = 0; j < 4; ++j)
                out[(size_t)(r0 + j) * ON_ + o] = acc[m][n][j] + bv;
        }
    }
}

extern "C" void kernel_launch(void* const* d_in, const int* in_sizes, int n_in,
                              void* d_out, int out_size, void* d_ws, size_t ws_size,
                              hipStream_t stream) {
    const float* x      = (const float*)d_in[0];
    const float* edge_w = (const float*)d_in[1];
    const float* edge_b = (const float*)d_in[2];
    const float* comb_w = (const float*)d_in[3];
    float* out = (float*)d_out;

    char* ws = (char*)d_ws;
    char* Bpk   = ws;                        // 1536*512*2 = 1,572,864 B
    float* bias = (float*)(ws + 1572864);    // 512*4 B

    hipLaunchKernelGGL(pack_B_bias, dim3(128 + 8), dim3(256), 0, stream, edge_w, comb_w, edge_b, (uint4*)Bpk, bias);
    hipLaunchKernelGGL(gemm_fused, dim3(512), dim3(256), 0, stream, x, Bpk, bias, out);
}